// Round 3
// baseline (316.327 us; speedup 1.0000x reference)
//
#include <hip/hip_runtime.h>

typedef __attribute__((ext_vector_type(8))) short  bf16x8;
typedef __attribute__((ext_vector_type(8))) unsigned short u16x8;
typedef __attribute__((ext_vector_type(4))) float  f32x4;

constexpr int S    = 4096;
constexpr int NR   = 4093;
constexpr int KAPP = 10000;
constexpr int KPAD = 10112;   // Bp padded k-extent (zeros beyond 10000)
constexpr int EAPP = 256;
constexpr int ETIM = 64;
constexpr int DIN  = 320;
constexpr int NDEC = 10000;
constexpr int NSK  = 8;       // split-K slices for app GEMM
constexpr int KCH  = 1256;    // k-chunk (multiple of 8; 8*1256 >= 10000)

__device__ inline unsigned short f2bf(float f) {
    unsigned u = __float_as_uint(f);
    u += 0x7fffu + ((u >> 16) & 1u);      // RTN-even
    return (unsigned short)(u >> 16);
}
__device__ inline float bf2f(unsigned short h) {
    return __uint_as_float(((unsigned)h) << 16);
}
__device__ inline u16x8 pack8(f32x4 a, f32x4 b) {
    u16x8 v;
    v[0]=f2bf(a.x); v[1]=f2bf(a.y); v[2]=f2bf(a.z); v[3]=f2bf(a.w);
    v[4]=f2bf(b.x); v[5]=f2bf(b.y); v[6]=f2bf(b.z); v[7]=f2bf(b.w);
    return v;
}
__device__ inline bf16x8 as_bf(u16x8 v) {
    union { u16x8 u; bf16x8 b; } c; c.u = v; return c.b;
}

// -------------------------------------------------- fp32 -> bf16 bulk convert
__global__ __launch_bounds__(256) void k_cvt_bf16(
    const float* __restrict__ in, unsigned short* __restrict__ out, int n8)
{
    int id = blockIdx.x * 256 + threadIdx.x;
    if (id >= n8) return;
    const float* p = in + (size_t)id * 8;
    f32x4 a = *reinterpret_cast<const f32x4*>(p);
    f32x4 b = *reinterpret_cast<const f32x4*>(p + 4);
    *reinterpret_cast<u16x8*>(out + (size_t)id * 8) = pack8(a, b);
}

// ------------------------------- emb_app_w [10000][256] -> Bp bf16 [256][10112]
__global__ __launch_bounds__(256) void k_transpose_appw(
    const float* __restrict__ B, unsigned short* __restrict__ Bp)
{
    __shared__ float T[64][68];
    const int kt = blockIdx.x * 64, nt = blockIdx.y * 64;
    const int tid = threadIdx.x;
    #pragma unroll
    for (int i = 0; i < 4; ++i) {
        int c = tid + (i << 8);
        int k = c >> 4, n4 = (c & 15) << 2;
        f32x4 v = {0.f, 0.f, 0.f, 0.f};
        if (kt + k < KAPP)
            v = *reinterpret_cast<const f32x4*>(&B[(size_t)(kt + k) * EAPP + nt + n4]);
        *reinterpret_cast<f32x4*>(&T[k][n4]) = v;
    }
    __syncthreads();
    #pragma unroll
    for (int i = 0; i < 2; ++i) {
        int c = tid + (i << 8);
        int n = c >> 3, ko = (c & 7) << 3;
        u16x8 v;
        #pragma unroll
        for (int j = 0; j < 8; ++j) v[j] = f2bf(T[ko + j][n]);
        *reinterpret_cast<u16x8*>(&Bp[(size_t)(nt + n) * KPAD + kt + ko]) = v;
    }
}

// ---------------------------------------------------------------- embeddings
__global__ __launch_bounds__(256) void k_embed_tim(
    const int* __restrict__ tim, const float* __restrict__ emb_tim,
    unsigned short* __restrict__ xb)
{
    int r = blockIdx.x * 4 + (threadIdx.x >> 6);
    int e = threadIdx.x & 63;
    xb[(size_t)r * DIN + EAPP + e] = f2bf(emb_tim[tim[r] * ETIM + e]);
}
__global__ __launch_bounds__(256) void k_embed_ptim(
    const int* __restrict__ ptim, const float* __restrict__ emb_tim,
    unsigned short* __restrict__ yb)
{
    int r = blockIdx.x * 4 + (threadIdx.x >> 6);
    int e = threadIdx.x & 63;
    if (r < NR) yb[(size_t)r * DIN + EAPP + e] = f2bf(emb_tim[ptim[r] * ETIM + e]);
}

// -------------------------------------- app GEMM step (direct-global, no LDS)
template<bool TAIL>
__device__ __forceinline__ void app_step(
    const float* __restrict__ A, const unsigned short* __restrict__ Bp,
    int kt, int kend, int bm, int wc, int rl, int kh8, f32x4 (&acc)[4][4])
{
    #pragma unroll
    for (int h = 0; h < 2; ++h) {
        const int kg = kt + h * 32 + kh8;
        bf16x8 af[4], bfr[4];
        #pragma unroll
        for (int i = 0; i < 4; ++i) {
            u16x8 v = {0,0,0,0,0,0,0,0};
            if (!TAIL || kg + 8 <= kend) {
                const float* p = A + (size_t)(bm + i * 16 + rl) * KAPP + kg;
                v = pack8(*reinterpret_cast<const f32x4*>(p),
                          *reinterpret_cast<const f32x4*>(p + 4));
            }
            af[i] = as_bf(v);
        }
        #pragma unroll
        for (int j = 0; j < 4; ++j)
            bfr[j] = *reinterpret_cast<const bf16x8*>(
                &Bp[(size_t)(wc + j * 16 + rl) * KPAD + kg]);   // zeros past 10000
        #pragma unroll
        for (int i = 0; i < 4; ++i)
            #pragma unroll
            for (int j = 0; j < 4; ++j)
                acc[i][j] = __builtin_amdgcn_mfma_f32_16x16x32_bf16(
                    af[i], bfr[j], acc[i][j], 0, 0, 0);
    }
}

// ------------------------- app GEMM: split-K x8, tile 64x256, barrier-free
__global__ __launch_bounds__(256) void k_gemm_app_direct(
    const float* __restrict__ A, const unsigned short* __restrict__ Bp,
    float* __restrict__ part)
{
    const int tid = threadIdx.x, lane = tid & 63, w = tid >> 6;
    const int ks = blockIdx.x, bm = blockIdx.y << 6;
    const int wc = w << 6, rl = lane & 15, kh8 = (lane >> 4) << 3;
    const int k0 = ks * KCH;
    const int kend = min(k0 + KCH, KAPP);
    const int nfull = (kend - k0) >> 6;     // 19 (ks<7) or 18 (ks=7)

    f32x4 acc[4][4];
    #pragma unroll
    for (int i = 0; i < 4; ++i)
        #pragma unroll
        for (int j = 0; j < 4; ++j) acc[i][j] = (f32x4){0.f, 0.f, 0.f, 0.f};

    for (int s = 0; s < nfull; ++s)
        app_step<false>(A, Bp, k0 + (s << 6), kend, bm, wc, rl, kh8, acc);
    app_step<true>(A, Bp, k0 + (nfull << 6), kend, bm, wc, rl, kh8, acc);

    float* P = part + ((size_t)ks * S + bm) * EAPP;
    const int rq = (lane >> 4) << 2;
    #pragma unroll
    for (int i = 0; i < 4; ++i)
        #pragma unroll
        for (int j = 0; j < 4; ++j) {
            int col = wc + j * 16 + rl;
            #pragma unroll
            for (int q = 0; q < 4; ++q)
                P[(size_t)(i * 16 + rq + q) * EAPP + col] = acc[i][j][q];
        }
}

// ----------------------------------- reduce split-K partials -> xb[:,0:256]
__global__ __launch_bounds__(256) void k_reduce_app(
    const float* __restrict__ part, unsigned short* __restrict__ xb)
{
    int id = blockIdx.x * 256 + threadIdx.x;   // 262144 = 4096*64
    int row = id >> 6, c4 = (id & 63) << 2;
    f32x4 s = {0.f, 0.f, 0.f, 0.f};
    #pragma unroll
    for (int sl = 0; sl < NSK; ++sl) {
        f32x4 v = *reinterpret_cast<const f32x4*>(
            &part[((size_t)sl * S + row) * EAPP + c4]);
        s.x += v.x; s.y += v.y; s.z += v.z; s.w += v.w;
    }
    unsigned short* o = &xb[(size_t)row * DIN + c4];
    o[0] = f2bf(s.x); o[1] = f2bf(s.y); o[2] = f2bf(s.z); o[3] = f2bf(s.w);
}

// ------------------------------------------------- attention score + pooling
__global__ __launch_bounds__(256) void k_score(
    const unsigned short* __restrict__ xb, const float* __restrict__ W,
    float* __restrict__ s)
{
    int wv = threadIdx.x >> 6, lane = threadIdx.x & 63;
    int m = blockIdx.x * 4 + wv;
    float sum = 0.f;
    #pragma unroll
    for (int i = 0; i < 5; ++i) {
        int k = lane + (i << 6);
        sum += bf2f(xb[(size_t)m * DIN + k]) * W[k];
    }
    #pragma unroll
    for (int off = 32; off; off >>= 1) sum += __shfl_down(sum, off);
    if (lane == 0) s[m] = sum;
}

__global__ void k_pooled(
    const unsigned short* __restrict__ xb, const float* __restrict__ s,
    const float* __restrict__ attn_b, unsigned short* __restrict__ pooledb)
{
    int n = blockIdx.x, d = threadIdx.x;
    float h[4], den = 0.f;
    #pragma unroll
    for (int f = 0; f < 4; ++f) {
        h[f] = tanhf(s[n + f] + attn_b[f]);
        den += fabsf(h[f]);
    }
    float inv = 1.f / den, p = 0.f;
    #pragma unroll
    for (int f = 0; f < 4; ++f)
        p = fmaf(h[f] * inv, bf2f(xb[(size_t)(n + f) * DIN + d]), p);
    pooledb[(size_t)n * DIN + d] = f2bf(p);
}

// ------------------------- NT GEMM, direct-global, tile 128x128, K=DIN=320
// C[m,j] = epi( sum_k A[m,k]*B[j,k] ).  A bf16 [4096][320], B bf16 [Nb][320].
// EPI 1: (acc+bias[j])*uid_emb[j] -> bf16. EPI 2: sigmoid -> f32.
template<int EPI>
__global__ __launch_bounds__(256) void k_gemm_nt_direct(
    const unsigned short* __restrict__ A, const unsigned short* __restrict__ B,
    int Nb, int Mlim,
    const float* __restrict__ bias,
    const float* __restrict__ emb_uid, const int* __restrict__ uid,
    void* __restrict__ Cout, int ldc)
{
    const int tid = threadIdx.x, lane = tid & 63, w = tid >> 6;
    const int bn = blockIdx.x << 7, bm = blockIdx.y << 7;
    const int wr = (w >> 1) << 6, wc = (w & 1) << 6;
    const int rl = lane & 15, kh8 = (lane >> 4) << 3;

    f32x4 acc[4][4];
    #pragma unroll
    for (int i = 0; i < 4; ++i)
        #pragma unroll
        for (int j = 0; j < 4; ++j) acc[i][j] = (f32x4){0.f, 0.f, 0.f, 0.f};

    #pragma unroll
    for (int s = 0; s < DIN / 64; ++s) {
        #pragma unroll
        for (int h = 0; h < 2; ++h) {
            const int kg = (s << 6) + h * 32 + kh8;
            bf16x8 af[4], bfr[4];
            #pragma unroll
            for (int i = 0; i < 4; ++i)
                af[i] = *reinterpret_cast<const bf16x8*>(
                    &A[(size_t)(bm + wr + i * 16 + rl) * DIN + kg]);
            #pragma unroll
            for (int j = 0; j < 4; ++j) {
                int brow = bn + wc + j * 16 + rl;
                u16x8 v = {0,0,0,0,0,0,0,0};
                if (brow < Nb)
                    v = *reinterpret_cast<const u16x8*>(&B[(size_t)brow * DIN + kg]);
                bfr[j] = as_bf(v);
            }
            #pragma unroll
            for (int i = 0; i < 4; ++i)
                #pragma unroll
                for (int j = 0; j < 4; ++j)
                    acc[i][j] = __builtin_amdgcn_mfma_f32_16x16x32_bf16(
                        af[i], bfr[j], acc[i][j], 0, 0, 0);
        }
    }

    const int rq = (lane >> 4) << 2;
    if (EPI == 1) {
        unsigned short* C = (unsigned short*)Cout;
        const float* us = emb_uid + (size_t)uid[0] * EAPP;
        #pragma unroll
        for (int j = 0; j < 4; ++j) {
            int col = bn + wc + j * 16 + rl;
            float um = us[col], bb = bias[col];
            #pragma unroll
            for (int i = 0; i < 4; ++i)
                #pragma unroll
                for (int q = 0; q < 4; ++q) {
                    int row = bm + wr + i * 16 + rq + q;
                    C[(size_t)row * ldc + col] = f2bf((acc[i][j][q] + bb) * um);
                }
        }
    } else {
        float* C = (float*)Cout;
        #pragma unroll
        for (int j = 0; j < 4; ++j) {
            int col = bn + wc + j * 16 + rl;
            if (col >= Nb) continue;
            float bb = bias[col];
            #pragma unroll
            for (int i = 0; i < 4; ++i)
                #pragma unroll
                for (int q = 0; q < 4; ++q) {
                    int row = bm + wr + i * 16 + rq + q;
                    if (row < Mlim) {
                        float v = acc[i][j][q] + bb;
                        C[(size_t)row * ldc + col] = 1.f / (1.f + __expf(-v));
                    }
                }
        }
    }
}

// ---------------------------------------------------------------- launcher
extern "C" void kernel_launch(void* const* d_in, const int* in_sizes, int n_in,
                              void* d_out, int out_size, void* d_ws, size_t ws_size,
                              hipStream_t stream)
{
    const int*   tim       = (const int*)  d_in[0];
    const float* app       = (const float*)d_in[1];
    const int*   uid       = (const int*)  d_in[3];
    const int*   ptim      = (const int*)  d_in[4];
    const float* emb_tim_w = (const float*)d_in[5];
    const float* emb_uid_w = (const float*)d_in[6];
    const float* emb_app_w = (const float*)d_in[7];
    const float* attn_W    = (const float*)d_in[8];
    const float* attn_b    = (const float*)d_in[9];
    const float* attn_fc_w = (const float*)d_in[10];
    const float* attn_fc_b = (const float*)d_in[11];
    const float* dec_w     = (const float*)d_in[12];
    const float* dec_b     = (const float*)d_in[13];
    float* out = (float*)d_out;

    char* w = (char*)d_ws;
    size_t o = 0;
    auto alloc = [&](size_t bytes) { char* p = w + o; o = (o + bytes + 511) & ~(size_t)511; return p; };
    unsigned short* xb      = (unsigned short*)alloc((size_t)S * DIN * 2);
    unsigned short* pooledb = (unsigned short*)alloc((size_t)S * DIN * 2);
    unsigned short* yb      = (unsigned short*)alloc((size_t)S * DIN * 2);
    float*          s       = (float*)        alloc((size_t)S * 4);
    unsigned short* Bp      = (unsigned short*)alloc((size_t)EAPP * KPAD * 2);
    unsigned short* decb    = (unsigned short*)alloc((size_t)NDEC * DIN * 2);
    unsigned short* fcb     = (unsigned short*)alloc((size_t)EAPP * DIN * 2);
    float*          part    = (float*)        alloc((size_t)NSK * S * EAPP * 4);

    // independent weight prep
    k_cvt_bf16<<<(NDEC * DIN / 8 + 255) / 256, 256, 0, stream>>>(dec_w, decb, NDEC * DIN / 8);
    k_cvt_bf16<<<(EAPP * DIN / 8 + 255) / 256, 256, 0, stream>>>(attn_fc_w, fcb, EAPP * DIN / 8);
    dim3 gT(KPAD / 64, EAPP / 64);
    k_transpose_appw<<<gT, 256, 0, stream>>>(emb_app_w, Bp);
    k_embed_tim<<<S / 4, 256, 0, stream>>>(tim, emb_tim_w, xb);

    // x[:,0:256] = app @ emb_app_w   (barrier-free split-K MFMA + reduce)
    dim3 gApp(NSK, S / 64);
    k_gemm_app_direct<<<gApp, 256, 0, stream>>>(app, Bp, part);
    k_reduce_app<<<S * 64 / 256, 256, 0, stream>>>(part, xb);

    // attention
    k_score<<<S / 4, 256, 0, stream>>>(xb, attn_W, s);
    k_pooled<<<NR, DIN, 0, stream>>>(xb, s, attn_b, pooledb);
    k_embed_ptim<<<S / 4, 256, 0, stream>>>(ptim, emb_tim_w, yb);

    // y[:,0:256] = (pooled @ fc^T + b) * uid_emb
    dim3 gFc(EAPP / 128, S / 128);
    k_gemm_nt_direct<1><<<gFc, 256, 0, stream>>>(pooledb, fcb, EAPP, S,
                                                 attn_fc_b, emb_uid_w, uid, yb, DIN);
    // score = sigmoid(y @ dec_w^T + dec_b)
    dim3 gDec((NDEC + 127) / 128, S / 128);
    k_gemm_nt_direct<2><<<gDec, 256, 0, stream>>>(yb, decb, NDEC, NR,
                                                  dec_b, nullptr, nullptr, out, NDEC);
}

// Round 4
// 284.741 us; speedup vs baseline: 1.1109x; 1.1109x over previous
//
#include <hip/hip_runtime.h>

typedef __attribute__((ext_vector_type(8))) short  bf16x8;
typedef __attribute__((ext_vector_type(8))) unsigned short u16x8;
typedef __attribute__((ext_vector_type(4))) float  f32x4;

constexpr int S    = 4096;
constexpr int NR   = 4093;
constexpr int KAPP = 10000;
constexpr int KPAD = 10240;   // Bp padded k-extent (zeros beyond 10000)
constexpr int EAPP = 256;
constexpr int ETIM = 64;
constexpr int DIN  = 320;
constexpr int NDEC = 10000;
constexpr int NSK  = 8;       // split-K slices for app GEMM
constexpr int KCH  = 1280;    // k-chunk per slice (even # of 32-steps everywhere)
constexpr int LDA2 = 328;     // LDS A-tile stride in halves (bank-clean)

__device__ inline unsigned short f2bf(float f) {
    unsigned u = __float_as_uint(f);
    u += 0x7fffu + ((u >> 16) & 1u);      // RTN-even
    return (unsigned short)(u >> 16);
}
__device__ inline float bf2f(unsigned short h) {
    return __uint_as_float(((unsigned)h) << 16);
}
__device__ inline u16x8 pack8(f32x4 a, f32x4 b) {
    u16x8 v;
    v[0]=f2bf(a.x); v[1]=f2bf(a.y); v[2]=f2bf(a.z); v[3]=f2bf(a.w);
    v[4]=f2bf(b.x); v[5]=f2bf(b.y); v[6]=f2bf(b.z); v[7]=f2bf(b.w);
    return v;
}
__device__ inline bf16x8 as_bf(u16x8 v) {
    union { u16x8 u; bf16x8 b; } c; c.u = v; return c.b;
}

// -------------------------------------------------- fp32 -> bf16 bulk convert
__global__ __launch_bounds__(256) void k_cvt_bf16(
    const float* __restrict__ in, unsigned short* __restrict__ out, int n8)
{
    int id = blockIdx.x * 256 + threadIdx.x;
    if (id >= n8) return;
    const float* p = in + (size_t)id * 8;
    f32x4 a = *reinterpret_cast<const f32x4*>(p);
    f32x4 b = *reinterpret_cast<const f32x4*>(p + 4);
    *reinterpret_cast<u16x8*>(out + (size_t)id * 8) = pack8(a, b);
}

// ------------------------------- emb_app_w [10000][256] -> Bp bf16 [256][10240]
__global__ __launch_bounds__(256) void k_transpose_appw(
    const float* __restrict__ B, unsigned short* __restrict__ Bp)
{
    __shared__ float T[64][68];
    const int kt = blockIdx.x * 64, nt = blockIdx.y * 64;
    const int tid = threadIdx.x;
    #pragma unroll
    for (int i = 0; i < 4; ++i) {
        int c = tid + (i << 8);
        int k = c >> 4, n4 = (c & 15) << 2;
        f32x4 v = {0.f, 0.f, 0.f, 0.f};
        if (kt + k < KAPP)
            v = *reinterpret_cast<const f32x4*>(&B[(size_t)(kt + k) * EAPP + nt + n4]);
        *reinterpret_cast<f32x4*>(&T[k][n4]) = v;
    }
    __syncthreads();
    #pragma unroll
    for (int i = 0; i < 2; ++i) {
        int c = tid + (i << 8);
        int n = c >> 3, ko = (c & 7) << 3;
        u16x8 v;
        #pragma unroll
        for (int j = 0; j < 8; ++j) v[j] = f2bf(T[ko + j][n]);
        *reinterpret_cast<u16x8*>(&Bp[(size_t)(nt + n) * KPAD + kt + ko]) = v;
    }
}

// ---------------------------------------------------------------- embeddings
__global__ __launch_bounds__(256) void k_embed_tim(
    const int* __restrict__ tim, const float* __restrict__ emb_tim,
    unsigned short* __restrict__ xb)
{
    int r = blockIdx.x * 4 + (threadIdx.x >> 6);
    int e = threadIdx.x & 63;
    xb[(size_t)r * DIN + EAPP + e] = f2bf(emb_tim[tim[r] * ETIM + e]);
}
__global__ __launch_bounds__(256) void k_embed_ptim(
    const int* __restrict__ ptim, const float* __restrict__ emb_tim,
    unsigned short* __restrict__ yb)
{
    int r = blockIdx.x * 4 + (threadIdx.x >> 6);
    int e = threadIdx.x & 63;
    if (r < NR) yb[(size_t)r * DIN + EAPP + e] = f2bf(emb_tim[ptim[r] * ETIM + e]);
}

// ------------------- app GEMM: split-K x8, tile 64x256, reg double-buffered
__global__ __launch_bounds__(256) void k_app(
    const float* __restrict__ A, const unsigned short* __restrict__ Bp,
    float* __restrict__ part)
{
    const int tid = threadIdx.x, lane = tid & 63, w = tid >> 6;
    const int ks = blockIdx.x, bm = blockIdx.y << 6;
    const int wc = w << 6;
    const int rl = lane & 15, kh8 = (lane >> 4) << 3;
    const int k0 = ks * KCH;
    const int kend = min(k0 + KCH, KAPP);
    const int nfull = (kend - k0) >> 5;          // 40 (ks<7) or 32 (ks=7): even

    f32x4 acc[4][4];
    #pragma unroll
    for (int i = 0; i < 4; ++i)
        #pragma unroll
        for (int j = 0; j < 4; ++j) acc[i][j] = (f32x4){0.f, 0.f, 0.f, 0.f};

    f32x4 a0[4][2], a1[4][2];
    u16x8 b0[4], b1[4];

#define LOADF(AS, BS, KG) do {                                                  \
    _Pragma("unroll")                                                           \
    for (int i = 0; i < 4; ++i) {                                               \
        const float* p = A + (size_t)(bm + i * 16 + rl) * KAPP + (KG) + kh8;    \
        AS[i][0] = *reinterpret_cast<const f32x4*>(p);                          \
        AS[i][1] = *reinterpret_cast<const f32x4*>(p + 4);                      \
    }                                                                           \
    _Pragma("unroll")                                                           \
    for (int j = 0; j < 4; ++j)                                                 \
        BS[j] = *reinterpret_cast<const u16x8*>(                                \
            &Bp[(size_t)(wc + j * 16 + rl) * KPAD + (KG) + kh8]);               \
} while (0)

#define STEP(AS, BS) do {                                                      \
    bf16x8 af[4], bfr[4];                                                       \
    _Pragma("unroll")                                                           \
    for (int i = 0; i < 4; ++i) af[i] = as_bf(pack8(AS[i][0], AS[i][1]));       \
    _Pragma("unroll")                                                           \
    for (int j = 0; j < 4; ++j) bfr[j] = as_bf(BS[j]);                          \
    _Pragma("unroll")                                                           \
    for (int i = 0; i < 4; ++i)                                                 \
        _Pragma("unroll")                                                       \
        for (int j = 0; j < 4; ++j)                                             \
            acc[i][j] = __builtin_amdgcn_mfma_f32_16x16x32_bf16(                \
                af[i], bfr[j], acc[i][j], 0, 0, 0);                             \
} while (0)

    LOADF(a0, b0, k0);
    for (int s = 0; s < nfull; s += 2) {
        LOADF(a1, b1, k0 + ((s + 1) << 5));
        STEP(a0, b0);
        if (s + 2 < nfull) LOADF(a0, b0, k0 + ((s + 2) << 5));
        STEP(a1, b1);
    }
    if (kend - k0 > (nfull << 5)) {   // guarded tail (slice 7: k 9984..10015)
        const int kg = k0 + (nfull << 5) + kh8;
        bf16x8 af[4], bfr[4];
        #pragma unroll
        for (int i = 0; i < 4; ++i) {
            u16x8 v = {0,0,0,0,0,0,0,0};
            if (kg + 8 <= KAPP) {
                const float* p = A + (size_t)(bm + i * 16 + rl) * KAPP + kg;
                v = pack8(*reinterpret_cast<const f32x4*>(p),
                          *reinterpret_cast<const f32x4*>(p + 4));
            }
            af[i] = as_bf(v);
        }
        #pragma unroll
        for (int j = 0; j < 4; ++j)
            bfr[j] = *reinterpret_cast<const bf16x8*>(
                &Bp[(size_t)(wc + j * 16 + rl) * KPAD + kg]);
        #pragma unroll
        for (int i = 0; i < 4; ++i)
            #pragma unroll
            for (int j = 0; j < 4; ++j)
                acc[i][j] = __builtin_amdgcn_mfma_f32_16x16x32_bf16(
                    af[i], bfr[j], acc[i][j], 0, 0, 0);
    }
#undef LOADF
#undef STEP

    float* P = part + ((size_t)ks * S + bm) * EAPP;
    const int rq = (lane >> 4) << 2;
    #pragma unroll
    for (int i = 0; i < 4; ++i)
        #pragma unroll
        for (int j = 0; j < 4; ++j) {
            int col = wc + j * 16 + rl;
            #pragma unroll
            for (int q = 0; q < 4; ++q)
                P[(size_t)(i * 16 + rq + q) * EAPP + col] = acc[i][j][q];
        }
}

// ----------------------------------- reduce split-K partials -> xb[:,0:256]
__global__ __launch_bounds__(256) void k_reduce_app(
    const float* __restrict__ part, unsigned short* __restrict__ xb)
{
    int id = blockIdx.x * 256 + threadIdx.x;   // 262144 = 4096*64
    int row = id >> 6, c4 = (id & 63) << 2;
    f32x4 s = {0.f, 0.f, 0.f, 0.f};
    #pragma unroll
    for (int sl = 0; sl < NSK; ++sl) {
        f32x4 v = *reinterpret_cast<const f32x4*>(
            &part[((size_t)sl * S + row) * EAPP + c4]);
        s.x += v.x; s.y += v.y; s.z += v.z; s.w += v.w;
    }
    unsigned short* o = &xb[(size_t)row * DIN + c4];
    o[0] = f2bf(s.x); o[1] = f2bf(s.y); o[2] = f2bf(s.z); o[3] = f2bf(s.w);
}

// ------------------------------------------------- attention score + pooling
__global__ __launch_bounds__(256) void k_score(
    const unsigned short* __restrict__ xb, const float* __restrict__ W,
    float* __restrict__ s)
{
    int wv = threadIdx.x >> 6, lane = threadIdx.x & 63;
    int m = blockIdx.x * 4 + wv;
    float sum = 0.f;
    #pragma unroll
    for (int i = 0; i < 5; ++i) {
        int k = lane + (i << 6);
        sum += bf2f(xb[(size_t)m * DIN + k]) * W[k];
    }
    #pragma unroll
    for (int off = 32; off; off >>= 1) sum += __shfl_down(sum, off);
    if (lane == 0) s[m] = sum;
}

__global__ void k_pooled(
    const unsigned short* __restrict__ xb, const float* __restrict__ s,
    const float* __restrict__ attn_b, unsigned short* __restrict__ pooledb)
{
    int n = blockIdx.x, d = threadIdx.x;
    float h[4], den = 0.f;
    #pragma unroll
    for (int f = 0; f < 4; ++f) {
        h[f] = tanhf(s[n + f] + attn_b[f]);
        den += fabsf(h[f]);
    }
    float inv = 1.f / den, p = 0.f;
    #pragma unroll
    for (int f = 0; f < 4; ++f)
        p = fmaf(h[f] * inv, bf2f(xb[(size_t)(n + f) * DIN + d]), p);
    pooledb[(size_t)n * DIN + d] = f2bf(p);
}

// ------------------- NT GEMM, K=320: A-tile staged ONCE in LDS, B streamed
// tile 64 rows x 256 cols, 4 waves; bijective XCD swizzle with bm fastest.
// EPI 1: (acc+bias[j])*uid_emb[j] -> bf16. EPI 2: sigmoid(acc+bias[j]) -> f32.
template<int EPI>
__global__ __launch_bounds__(256) void k_nt320(
    const unsigned short* __restrict__ A, const unsigned short* __restrict__ B,
    int Nb, int Mlim,
    const float* __restrict__ bias,
    const float* __restrict__ emb_uid, const int* __restrict__ uid,
    void* __restrict__ Cout, int ldc)
{
    __shared__ unsigned short As[64 * LDA2];
    const int tid = threadIdx.x, lane = tid & 63, w = tid >> 6;
    const int qx = gridDim.x >> 3;                 // nwg % 8 == 0 always here
    const int swz = (blockIdx.x & 7) * qx + (blockIdx.x >> 3);
    const int bm = (swz & 63) << 6, bn = (swz >> 6) << 8;
    const int rl = lane & 15, kh8 = (lane >> 4) << 3;
    const int wc = w << 6;

    {   // stage A-tile (64 x 320 bf16 = 40 KB) once
        const int row = tid >> 2, c0 = tid & 3;
        const unsigned short* src = A + (size_t)(bm + row) * DIN;
        unsigned short* dst = As + row * LDA2;
        #pragma unroll
        for (int t = 0; t < 10; ++t) {
            int ch = (c0 + (t << 2)) << 3;
            *reinterpret_cast<u16x8*>(dst + ch) =
                *reinterpret_cast<const u16x8*>(src + ch);
        }
    }
    __syncthreads();

    f32x4 acc[4][4];
    #pragma unroll
    for (int i = 0; i < 4; ++i)
        #pragma unroll
        for (int j = 0; j < 4; ++j) acc[i][j] = (f32x4){0.f, 0.f, 0.f, 0.f};

    #pragma unroll
    for (int ksn = 0; ksn < 10; ++ksn) {
        const int kg = (ksn << 5) + kh8;
        bf16x8 af[4], bfr[4];
        #pragma unroll
        for (int i = 0; i < 4; ++i)
            af[i] = *reinterpret_cast<const bf16x8*>(&As[(i * 16 + rl) * LDA2 + kg]);
        #pragma unroll
        for (int j = 0; j < 4; ++j) {
            int brow = bn + wc + j * 16 + rl;
            u16x8 v = {0,0,0,0,0,0,0,0};
            if (brow < Nb)
                v = *reinterpret_cast<const u16x8*>(&B[(size_t)brow * DIN + kg]);
            bfr[j] = as_bf(v);
        }
        #pragma unroll
        for (int i = 0; i < 4; ++i)
            #pragma unroll
            for (int j = 0; j < 4; ++j)
                acc[i][j] = __builtin_amdgcn_mfma_f32_16x16x32_bf16(
                    af[i], bfr[j], acc[i][j], 0, 0, 0);
    }

    const int rq = (lane >> 4) << 2;
    if (EPI == 1) {
        unsigned short* C = (unsigned short*)Cout;
        const float* us = emb_uid + (size_t)uid[0] * EAPP;
        #pragma unroll
        for (int j = 0; j < 4; ++j) {
            int col = bn + wc + j * 16 + rl;
            if (col >= Nb) continue;
            float um = us[col], bb = bias[col];
            #pragma unroll
            for (int i = 0; i < 4; ++i)
                #pragma unroll
                for (int q = 0; q < 4; ++q) {
                    int row = bm + i * 16 + rq + q;
                    if (row < Mlim)
                        C[(size_t)row * ldc + col] = f2bf((acc[i][j][q] + bb) * um);
                }
        }
    } else {
        float* C = (float*)Cout;
        #pragma unroll
        for (int j = 0; j < 4; ++j) {
            int col = bn + wc + j * 16 + rl;
            if (col >= Nb) continue;
            float bb = bias[col];
            #pragma unroll
            for (int i = 0; i < 4; ++i)
                #pragma unroll
                for (int q = 0; q < 4; ++q) {
                    int row = bm + i * 16 + rq + q;
                    if (row < Mlim) {
                        float v = acc[i][j][q] + bb;
                        C[(size_t)row * ldc + col] = 1.f / (1.f + __expf(-v));
                    }
                }
        }
    }
}

// ---------------------------------------------------------------- launcher
extern "C" void kernel_launch(void* const* d_in, const int* in_sizes, int n_in,
                              void* d_out, int out_size, void* d_ws, size_t ws_size,
                              hipStream_t stream)
{
    const int*   tim       = (const int*)  d_in[0];
    const float* app       = (const float*)d_in[1];
    const int*   uid       = (const int*)  d_in[3];
    const int*   ptim      = (const int*)  d_in[4];
    const float* emb_tim_w = (const float*)d_in[5];
    const float* emb_uid_w = (const float*)d_in[6];
    const float* emb_app_w = (const float*)d_in[7];
    const float* attn_W    = (const float*)d_in[8];
    const float* attn_b    = (const float*)d_in[9];
    const float* attn_fc_w = (const float*)d_in[10];
    const float* attn_fc_b = (const float*)d_in[11];
    const float* dec_w     = (const float*)d_in[12];
    const float* dec_b     = (const float*)d_in[13];
    float* out = (float*)d_out;

    char* w = (char*)d_ws;
    size_t o = 0;
    auto alloc = [&](size_t bytes) { char* p = w + o; o = (o + bytes + 511) & ~(size_t)511; return p; };
    unsigned short* xb      = (unsigned short*)alloc((size_t)S * DIN * 2);
    unsigned short* pooledb = (unsigned short*)alloc((size_t)S * DIN * 2);
    unsigned short* yb      = (unsigned short*)alloc((size_t)S * DIN * 2);
    float*          s       = (float*)        alloc((size_t)S * 4);
    unsigned short* Bp      = (unsigned short*)alloc((size_t)EAPP * KPAD * 2);
    unsigned short* decb    = (unsigned short*)alloc((size_t)NDEC * DIN * 2);
    unsigned short* fcb     = (unsigned short*)alloc((size_t)EAPP * DIN * 2);
    float*          part    = (float*)        alloc((size_t)NSK * S * EAPP * 4);

    // independent weight prep
    k_cvt_bf16<<<(NDEC * DIN / 8 + 255) / 256, 256, 0, stream>>>(dec_w, decb, NDEC * DIN / 8);
    k_cvt_bf16<<<(EAPP * DIN / 8 + 255) / 256, 256, 0, stream>>>(attn_fc_w, fcb, EAPP * DIN / 8);
    dim3 gT(KPAD / 64, EAPP / 64);
    k_transpose_appw<<<gT, 256, 0, stream>>>(emb_app_w, Bp);
    k_embed_tim<<<S / 4, 256, 0, stream>>>(tim, emb_tim_w, xb);

    // x[:,0:256] = app @ emb_app_w   (split-K MFMA, reg double-buffer + reduce)
    dim3 gApp(NSK, S / 64);
    k_app<<<gApp, 256, 0, stream>>>(app, Bp, part);
    k_reduce_app<<<S * 64 / 256, 256, 0, stream>>>(part, xb);

    // attention
    k_score<<<S / 4, 256, 0, stream>>>(xb, attn_W, s);
    k_pooled<<<NR, DIN, 0, stream>>>(xb, s, attn_b, pooledb);
    k_embed_ptim<<<S / 4, 256, 0, stream>>>(ptim, emb_tim_w, yb);

    // y[:,0:256] = (pooled @ fc^T + b) * uid_emb     (64 blocks)
    k_nt320<1><<<64, 256, 0, stream>>>(pooledb, fcb, EAPP, S,
                                       attn_fc_b, emb_uid_w, uid, yb, DIN);
    // score = sigmoid(y @ dec_w^T + dec_b)           (2560 blocks)
    k_nt320<2><<<40 * 64, 256, 0, stream>>>(yb, decb, NDEC, NR,
                                            dec_b, nullptr, nullptr, out, NDEC);
}

// Round 5
// 248.823 us; speedup vs baseline: 1.2713x; 1.1444x over previous
//
#include <hip/hip_runtime.h>

typedef __attribute__((ext_vector_type(8))) short  bf16x8;
typedef __attribute__((ext_vector_type(8))) unsigned short u16x8;
typedef __attribute__((ext_vector_type(4))) float  f32x4;

constexpr int S    = 4096;
constexpr int NR   = 4093;
constexpr int KAPP = 10000;
constexpr int EAPP = 256;
constexpr int ETIM = 64;
constexpr int DIN  = 320;
constexpr int NDEC = 10000;
constexpr int NSK  = 10;      // split-K slices for app GEMM
constexpr int KCH  = 1024;    // k-chunk per slice (32 steps, uniform)
constexpr int KPAD = NSK * KCH;   // 10240, Bp zero-padded past 10000
constexpr int NS   = KCH / 32;    // 32 K-steps per block
constexpr int LDP  = 40;      // k_app LDS row stride (bf16), 2-way banks = free
constexpr int LDA2 = 328;     // k_nt320 LDS A stride (bf16), 2-way banks = free

__device__ inline unsigned short f2bf(float f) {
    unsigned u = __float_as_uint(f);
    u += 0x7fffu + ((u >> 16) & 1u);      // RTN-even
    return (unsigned short)(u >> 16);
}
__device__ inline float bf2f(unsigned short h) {
    return __uint_as_float(((unsigned)h) << 16);
}
__device__ inline u16x8 pack8(f32x4 a, f32x4 b) {
    u16x8 v;
    v[0]=f2bf(a.x); v[1]=f2bf(a.y); v[2]=f2bf(a.z); v[3]=f2bf(a.w);
    v[4]=f2bf(b.x); v[5]=f2bf(b.y); v[6]=f2bf(b.z); v[7]=f2bf(b.w);
    return v;
}
__device__ inline bf16x8 as_bf(u16x8 v) {
    union { u16x8 u; bf16x8 b; } c; c.u = v; return c.b;
}

// -------------------------------------------------- fp32 -> bf16 bulk convert
__global__ __launch_bounds__(256) void k_cvt_bf16(
    const float* __restrict__ in, unsigned short* __restrict__ out, int n8)
{
    int id = blockIdx.x * 256 + threadIdx.x;
    if (id >= n8) return;
    const float* p = in + (size_t)id * 8;
    f32x4 a = *reinterpret_cast<const f32x4*>(p);
    f32x4 b = *reinterpret_cast<const f32x4*>(p + 4);
    *reinterpret_cast<u16x8*>(out + (size_t)id * 8) = pack8(a, b);
}

// ------------------------------- emb_app_w [10000][256] -> Bp bf16 [256][10240]
__global__ __launch_bounds__(256) void k_transpose_appw(
    const float* __restrict__ B, unsigned short* __restrict__ Bp)
{
    __shared__ float T[64][68];
    const int kt = blockIdx.x * 64, nt = blockIdx.y * 64;
    const int tid = threadIdx.x;
    #pragma unroll
    for (int i = 0; i < 4; ++i) {
        int c = tid + (i << 8);
        int k = c >> 4, n4 = (c & 15) << 2;
        f32x4 v = {0.f, 0.f, 0.f, 0.f};
        if (kt + k < KAPP)
            v = *reinterpret_cast<const f32x4*>(&B[(size_t)(kt + k) * EAPP + nt + n4]);
        *reinterpret_cast<f32x4*>(&T[k][n4]) = v;
    }
    __syncthreads();
    #pragma unroll
    for (int i = 0; i < 2; ++i) {
        int c = tid + (i << 8);
        int n = c >> 3, ko = (c & 7) << 3;
        u16x8 v;
        #pragma unroll
        for (int j = 0; j < 8; ++j) v[j] = f2bf(T[ko + j][n]);
        *reinterpret_cast<u16x8*>(&Bp[(size_t)(nt + n) * KPAD + kt + ko]) = v;
    }
}

// ---------------------------------------------------------------- embeddings
__global__ __launch_bounds__(256) void k_embed_tim(
    const int* __restrict__ tim, const float* __restrict__ emb_tim,
    unsigned short* __restrict__ xb)
{
    int r = blockIdx.x * 4 + (threadIdx.x >> 6);
    int e = threadIdx.x & 63;
    xb[(size_t)r * DIN + EAPP + e] = f2bf(emb_tim[tim[r] * ETIM + e]);
}
__global__ __launch_bounds__(256) void k_embed_ptim(
    const int* __restrict__ ptim, const float* __restrict__ emb_tim,
    unsigned short* __restrict__ yb)
{
    int r = blockIdx.x * 4 + (threadIdx.x >> 6);
    int e = threadIdx.x & 63;
    if (r < NR) yb[(size_t)r * DIN + EAPP + e] = f2bf(emb_tim[ptim[r] * ETIM + e]);
}

// ---------- app GEMM: split-K x10, tile 64x256, LDS dbuf, ONE barrier/step
__global__ __launch_bounds__(256, 3) void k_app(
    const float* __restrict__ A, const unsigned short* __restrict__ Bp,
    float* __restrict__ part)
{
    __shared__ unsigned short As[2][64 * LDP];
    __shared__ unsigned short Bs[2][256 * LDP];
    const int tid = threadIdx.x, lane = tid & 63, w = tid >> 6;
    const int ks = blockIdx.x, bm = blockIdx.y << 6;
    const int wc = w << 6, rl = lane & 15, kh8 = (lane >> 4) << 3;
    const int k0 = ks * KCH;
    const int arow = tid >> 2, ak0 = (tid & 3) << 3;   // A-stage coords (64x32)

    u16x8 ra, rb[4];
    auto gload = [&](int step) {
        const int kt = k0 + (step << 5);
        {
            const int k = kt + ak0;
            u16x8 v = {0,0,0,0,0,0,0,0};
            if (k < KAPP) {                           // zero-fill past 10000
                const float* p = &A[(size_t)(bm + arow) * KAPP + k];
                v = pack8(*reinterpret_cast<const f32x4*>(p),
                          *reinterpret_cast<const f32x4*>(p + 4));
            }
            ra = v;
        }
        #pragma unroll
        for (int i = 0; i < 4; ++i) {
            int c = tid + (i << 8);
            int row = c >> 2, ko = (c & 3) << 3;
            rb[i] = *reinterpret_cast<const u16x8*>(&Bp[(size_t)row * KPAD + kt + ko]);
        }
    };
    auto swrite = [&](int b) {
        *reinterpret_cast<u16x8*>(&As[b][arow * LDP + ak0]) = ra;
        #pragma unroll
        for (int i = 0; i < 4; ++i) {
            int c = tid + (i << 8);
            int row = c >> 2, ko = (c & 3) << 3;
            *reinterpret_cast<u16x8*>(&Bs[b][row * LDP + ko]) = rb[i];
        }
    };

    f32x4 acc[4][4];
    #pragma unroll
    for (int i = 0; i < 4; ++i)
        #pragma unroll
        for (int j = 0; j < 4; ++j) acc[i][j] = (f32x4){0.f, 0.f, 0.f, 0.f};

    gload(0); swrite(0); __syncthreads();
    for (int t = 0; t < NS; ++t) {
        const int cur = t & 1;
        const bool more = (t + 1 < NS);
        if (more) gload(t + 1);                       // issue next-step loads
        bf16x8 af[4], bfr[4];
        #pragma unroll
        for (int i = 0; i < 4; ++i)
            af[i] = *reinterpret_cast<const bf16x8*>(
                &As[cur][(i * 16 + rl) * LDP + kh8]);
        #pragma unroll
        for (int j = 0; j < 4; ++j)
            bfr[j] = *reinterpret_cast<const bf16x8*>(
                &Bs[cur][(wc + j * 16 + rl) * LDP + kh8]);
        #pragma unroll
        for (int i = 0; i < 4; ++i)
            #pragma unroll
            for (int j = 0; j < 4; ++j)
                acc[i][j] = __builtin_amdgcn_mfma_f32_16x16x32_bf16(
                    af[i], bfr[j], acc[i][j], 0, 0, 0);
        if (more) swrite(cur ^ 1);                    // write OTHER buffer
        __syncthreads();                              // one barrier per step
    }

    float* P = part + ((size_t)ks * S + bm) * EAPP;
    const int rq = (lane >> 4) << 2;
    #pragma unroll
    for (int i = 0; i < 4; ++i)
        #pragma unroll
        for (int j = 0; j < 4; ++j) {
            int col = wc + j * 16 + rl;
            #pragma unroll
            for (int q = 0; q < 4; ++q)
                P[(size_t)(i * 16 + rq + q) * EAPP + col] = acc[i][j][q];
        }
}

// ----------------------------------- reduce split-K partials -> xb[:,0:256]
__global__ __launch_bounds__(256) void k_reduce_app(
    const float* __restrict__ part, unsigned short* __restrict__ xb)
{
    int id = blockIdx.x * 256 + threadIdx.x;   // 262144 = 4096*64
    int row = id >> 6, c4 = (id & 63) << 2;
    f32x4 s = {0.f, 0.f, 0.f, 0.f};
    #pragma unroll
    for (int sl = 0; sl < NSK; ++sl) {
        f32x4 v = *reinterpret_cast<const f32x4*>(
            &part[((size_t)sl * S + row) * EAPP + c4]);
        s.x += v.x; s.y += v.y; s.z += v.z; s.w += v.w;
    }
    unsigned short* o = &xb[(size_t)row * DIN + c4];
    o[0] = f2bf(s.x); o[1] = f2bf(s.y); o[2] = f2bf(s.z); o[3] = f2bf(s.w);
}

// ------------------------------------------------- attention score + pooling
__global__ __launch_bounds__(256) void k_score(
    const unsigned short* __restrict__ xb, const float* __restrict__ W,
    float* __restrict__ s)
{
    int wv = threadIdx.x >> 6, lane = threadIdx.x & 63;
    int m = blockIdx.x * 4 + wv;
    float sum = 0.f;
    #pragma unroll
    for (int i = 0; i < 5; ++i) {
        int k = lane + (i << 6);
        sum += bf2f(xb[(size_t)m * DIN + k]) * W[k];
    }
    #pragma unroll
    for (int off = 32; off; off >>= 1) sum += __shfl_down(sum, off);
    if (lane == 0) s[m] = sum;
}

__global__ void k_pooled(
    const unsigned short* __restrict__ xb, const float* __restrict__ s,
    const float* __restrict__ attn_b, unsigned short* __restrict__ pooledb)
{
    int n = blockIdx.x, d = threadIdx.x;
    float h[4], den = 0.f;
    #pragma unroll
    for (int f = 0; f < 4; ++f) {
        h[f] = tanhf(s[n + f] + attn_b[f]);
        den += fabsf(h[f]);
    }
    float inv = 1.f / den, p = 0.f;
    #pragma unroll
    for (int f = 0; f < 4; ++f)
        p = fmaf(h[f] * inv, bf2f(xb[(size_t)(n + f) * DIN + d]), p);
    pooledb[(size_t)n * DIN + d] = f2bf(p);
}

// ------------------- NT GEMM, K=320: A-tile staged ONCE in LDS, B prefetched
// tile 64 rows x 256 cols, 4 waves; bijective XCD swizzle with bm fastest.
// EPI 1: (acc+bias[j])*uid_emb[j] -> bf16. EPI 2: sigmoid(acc+bias[j]) -> f32.
template<int EPI>
__global__ __launch_bounds__(256, 3) void k_nt320(
    const unsigned short* __restrict__ A, const unsigned short* __restrict__ B,
    int Nb, int Mlim,
    const float* __restrict__ bias,
    const float* __restrict__ emb_uid, const int* __restrict__ uid,
    void* __restrict__ Cout, int ldc)
{
    __shared__ unsigned short As[64 * LDA2];
    const int tid = threadIdx.x, lane = tid & 63, w = tid >> 6;
    const int qx = gridDim.x >> 3;                 // nwg % 8 == 0 always here
    const int swz = (blockIdx.x & 7) * qx + (blockIdx.x >> 3);
    const int bm = (swz & 63) << 6, bn = (swz >> 6) << 8;
    const int rl = lane & 15, kh8 = (lane >> 4) << 3;
    const int wc = w << 6;

    {   // stage A-tile (64 x 320 bf16 = 40 KB) once
        const int row = tid >> 2, c0 = tid & 3;
        const unsigned short* src = A + (size_t)(bm + row) * DIN;
        unsigned short* dst = As + row * LDA2;
        #pragma unroll
        for (int t = 0; t < 10; ++t) {
            int ch = (c0 + (t << 2)) << 3;
            *reinterpret_cast<u16x8*>(dst + ch) =
                *reinterpret_cast<const u16x8*>(src + ch);
        }
    }
    __syncthreads();

    f32x4 acc[4][4];
    #pragma unroll
    for (int i = 0; i < 4; ++i)
        #pragma unroll
        for (int j = 0; j < 4; ++j) acc[i][j] = (f32x4){0.f, 0.f, 0.f, 0.f};

    u16x8 b0[4], b1[4];
#define LOADB(DST, KSN) do {                                                    \
    const int kg_ = ((KSN) << 5) + kh8;                                         \
    _Pragma("unroll")                                                           \
    for (int j = 0; j < 4; ++j) {                                               \
        int brow = bn + wc + j * 16 + rl;                                       \
        u16x8 v_ = {0,0,0,0,0,0,0,0};                                           \
        if (brow < Nb)                                                          \
            v_ = *reinterpret_cast<const u16x8*>(&B[(size_t)brow * DIN + kg_]); \
        DST[j] = v_;                                                            \
    }                                                                           \
} while (0)

#define STEPNT(BARR, KSN) do {                                                  \
    const int kg_ = ((KSN) << 5) + kh8;                                         \
    bf16x8 af_[4];                                                              \
    _Pragma("unroll")                                                           \
    for (int i = 0; i < 4; ++i)                                                 \
        af_[i] = *reinterpret_cast<const bf16x8*>(                              \
            &As[(i * 16 + rl) * LDA2 + kg_]);                                   \
    _Pragma("unroll")                                                           \
    for (int i = 0; i < 4; ++i)                                                 \
        _Pragma("unroll")                                                       \
        for (int j = 0; j < 4; ++j)                                             \
            acc[i][j] = __builtin_amdgcn_mfma_f32_16x16x32_bf16(                \
                af_[i], as_bf(BARR[j]), acc[i][j], 0, 0, 0);                     \
} while (0)

    LOADB(b0, 0);
    #pragma unroll
    for (int p = 0; p < 5; ++p) {
        LOADB(b1, 2 * p + 1);
        STEPNT(b0, 2 * p);
        if (2 * p + 2 < 10) LOADB(b0, 2 * p + 2);
        STEPNT(b1, 2 * p + 1);
    }
#undef LOADB
#undef STEPNT

    const int rq = (lane >> 4) << 2;
    if (EPI == 1) {
        unsigned short* C = (unsigned short*)Cout;
        const float* us = emb_uid + (size_t)uid[0] * EAPP;
        #pragma unroll
        for (int j = 0; j < 4; ++j) {
            int col = bn + wc + j * 16 + rl;
            if (col >= Nb) continue;
            float um = us[col], bb = bias[col];
            #pragma unroll
            for (int i = 0; i < 4; ++i)
                #pragma unroll
                for (int q = 0; q < 4; ++q) {
                    int row = bm + i * 16 + rq + q;
                    if (row < Mlim)
                        C[(size_t)row * ldc + col] = f2bf((acc[i][j][q] + bb) * um);
                }
        }
    } else {
        float* C = (float*)Cout;
        #pragma unroll
        for (int j = 0; j < 4; ++j) {
            int col = bn + wc + j * 16 + rl;
            if (col >= Nb) continue;
            float bb = bias[col];
            #pragma unroll
            for (int i = 0; i < 4; ++i)
                #pragma unroll
                for (int q = 0; q < 4; ++q) {
                    int row = bm + i * 16 + rq + q;
                    if (row < Mlim) {
                        float v = acc[i][j][q] + bb;
                        C[(size_t)row * ldc + col] = 1.f / (1.f + __expf(-v));
                    }
                }
        }
    }
}

// ---------------------------------------------------------------- launcher
extern "C" void kernel_launch(void* const* d_in, const int* in_sizes, int n_in,
                              void* d_out, int out_size, void* d_ws, size_t ws_size,
                              hipStream_t stream)
{
    const int*   tim       = (const int*)  d_in[0];
    const float* app       = (const float*)d_in[1];
    const int*   uid       = (const int*)  d_in[3];
    const int*   ptim      = (const int*)  d_in[4];
    const float* emb_tim_w = (const float*)d_in[5];
    const float* emb_uid_w = (const float*)d_in[6];
    const float* emb_app_w = (const float*)d_in[7];
    const float* attn_W    = (const float*)d_in[8];
    const float* attn_b    = (const float*)d_in[9];
    const float* attn_fc_w = (const float*)d_in[10];
    const float* attn_fc_b = (const float*)d_in[11];
    const float* dec_w     = (const float*)d_in[12];
    const float* dec_b     = (const float*)d_in[13];
    float* out = (float*)d_out;

    char* w = (char*)d_ws;
    size_t o = 0;
    auto alloc = [&](size_t bytes) { char* p = w + o; o = (o + bytes + 511) & ~(size_t)511; return p; };
    unsigned short* xb      = (unsigned short*)alloc((size_t)S * DIN * 2);
    unsigned short* pooledb = (unsigned short*)alloc((size_t)S * DIN * 2);
    unsigned short* yb      = (unsigned short*)alloc((size_t)S * DIN * 2);
    float*          s       = (float*)        alloc((size_t)S * 4);
    unsigned short* Bp      = (unsigned short*)alloc((size_t)EAPP * KPAD * 2);
    unsigned short* decb    = (unsigned short*)alloc((size_t)NDEC * DIN * 2);
    unsigned short* fcb     = (unsigned short*)alloc((size_t)EAPP * DIN * 2);
    float*          part    = (float*)        alloc((size_t)NSK * S * EAPP * 4);

    // independent weight prep
    k_cvt_bf16<<<(NDEC * DIN / 8 + 255) / 256, 256, 0, stream>>>(dec_w, decb, NDEC * DIN / 8);
    k_cvt_bf16<<<(EAPP * DIN / 8 + 255) / 256, 256, 0, stream>>>(attn_fc_w, fcb, EAPP * DIN / 8);
    dim3 gT(KPAD / 64, EAPP / 64);
    k_transpose_appw<<<gT, 256, 0, stream>>>(emb_app_w, Bp);
    k_embed_tim<<<S / 4, 256, 0, stream>>>(tim, emb_tim_w, xb);

    // x[:,0:256] = app @ emb_app_w   (split-K x10, 1-barrier LDS dbuf + reduce)
    dim3 gApp(NSK, S / 64);
    k_app<<<gApp, 256, 0, stream>>>(app, Bp, part);
    k_reduce_app<<<S * 64 / 256, 256, 0, stream>>>(part, xb);

    // attention
    k_score<<<S / 4, 256, 0, stream>>>(xb, attn_W, s);
    k_pooled<<<NR, DIN, 0, stream>>>(xb, s, attn_b, pooledb);
    k_embed_ptim<<<S / 4, 256, 0, stream>>>(ptim, emb_tim_w, yb);

    // y[:,0:256] = (pooled @ fc^T + b) * uid_emb     (64 blocks)
    k_nt320<1><<<64, 256, 0, stream>>>(pooledb, fcb, EAPP, S,
                                       attn_fc_b, emb_uid_w, uid, yb, DIN);
    // score = sigmoid(y @ dec_w^T + dec_b)           (2560 blocks)
    k_nt320<2><<<40 * 64, 256, 0, stream>>>(yb, decb, NDEC, NR,
                                            dec_b, nullptr, nullptr, out, NDEC);
}